// Round 7
// baseline (391.810 us; speedup 1.0000x reference)
//
#include <hip/hip_runtime.h>

#define N_NODES   100000
#define N_EDGES   3200000
#define D_IN      128
#define H1F       32
#define H2F       64
#define N_CLASSES 10
#define N_GRAPHS  64

#define NBUCK 391      // ceil(100000 / 256) buckets of 256 nodes
#define NPB   1024     // partition blocks (4 blocks/CU)
#define EPB   (N_EDGES / NPB)   // 3125 edges per partition block (exact)

// bf16 helpers (RNE pack)
__device__ __forceinline__ unsigned f2bf(float f) {
    unsigned u = __float_as_uint(f);
    return (u + 0x7fffu + ((u >> 16) & 1u)) >> 16;
}
__device__ __forceinline__ float bf2f(unsigned h) {
    return __uint_as_float(h << 16);
}

// ---------------- tiny zero for bucket counters ----------------
__global__ void k_zero2(int* ccount, int* rcount) {
    int t = threadIdx.x;
    for (int i = t; i < NBUCK; i += 256) { ccount[i] = 0; rcount[i] = 0; }
}

// ---------------- pass 1: coarse bucket histograms (col and row) ----------------
__global__ __launch_bounds__(256) void k_coarse(const int* __restrict__ row,
        const int* __restrict__ col, int* ccount, int* rcount) {
    __shared__ int ch[NBUCK], rh[NBUCK];
    int t = threadIdx.x;
    for (int i = t; i < NBUCK; i += 256) { ch[i] = 0; rh[i] = 0; }
    __syncthreads();
    int s = blockIdx.x * EPB, e = s + EPB;
    for (int i = s + t; i < e; i += 256) {
        atomicAdd(&ch[col[i] >> 8], 1);
        atomicAdd(&rh[row[i] >> 8], 1);
    }
    __syncthreads();
    for (int i = t; i < NBUCK; i += 256) {
        if (ch[i]) atomicAdd(&ccount[i], ch[i]);
        if (rh[i]) atomicAdd(&rcount[i], rh[i]);
    }
}

// ---------------- pass 2: scan bucket counts -> offsets; misc init ----------------
__global__ __launch_bounds__(512) void k_cscan(const int* __restrict__ ccount,
        const int* __restrict__ rcount, int* coff, int* roff, int* cpos, int* rpos,
        float* sums, int* off) {
    __shared__ int sc[512], sr[512];
    int t = threadIdx.x;
    int vc = (t < NBUCK) ? ccount[t] : 0;
    int vr = (t < NBUCK) ? rcount[t] : 0;
    sc[t] = vc; sr[t] = vr; __syncthreads();
    for (int o = 1; o < 512; o <<= 1) {
        int a = (t >= o) ? sc[t - o] : 0;
        int b = (t >= o) ? sr[t - o] : 0;
        __syncthreads();
        sc[t] += a; sr[t] += b;
        __syncthreads();
    }
    if (t < NBUCK) {
        int ce = sc[t] - vc, re = sr[t] - vr;
        coff[t] = ce; cpos[t] = ce;
        roff[t] = re; rpos[t] = re;
    }
    if (t == 0) { coff[NBUCK] = N_EDGES; roff[NBUCK] = N_EDGES; off[N_NODES] = N_EDGES; }
    for (int i = t; i < N_GRAPHS * H2F; i += 512) sums[i] = 0.f;
}

// ---------------- pass 3: single-pass partition (col-keyed pairs, row bytes) ----------------
__global__ __launch_bounds__(256) void k_part(const int* __restrict__ row,
        const int* __restrict__ col, int* cpos, int* rpos,
        unsigned* __restrict__ partc, unsigned char* __restrict__ partr) {
    __shared__ int hc[NBUCK], bc[NBUCK], kc[NBUCK];
    __shared__ int hr[NBUCK], br[NBUCK], kr[NBUCK];
    int t = threadIdx.x;
    for (int i = t; i < NBUCK; i += 256) { hc[i] = 0; kc[i] = 0; hr[i] = 0; kr[i] = 0; }
    __syncthreads();
    int s = blockIdx.x * EPB, e = s + EPB;
    for (int i = s + t; i < e; i += 256) {
        atomicAdd(&hc[col[i] >> 8], 1);
        atomicAdd(&hr[row[i] >> 8], 1);
    }
    __syncthreads();
    for (int i = t; i < NBUCK; i += 256) {
        bc[i] = hc[i] ? atomicAdd(&cpos[i], hc[i]) : 0;
        br[i] = hr[i] ? atomicAdd(&rpos[i], hr[i]) : 0;
    }
    __syncthreads();
    for (int i = s + t; i < e; i += 256) {
        int c = col[i], r = row[i];
        int b = c >> 8;
        int k = atomicAdd(&kc[b], 1);
        partc[bc[b] + k] = ((unsigned)(c & 255) << 17) | (unsigned)r;  // row < 2^17
        int b2_ = r >> 8;
        int k2 = atomicAdd(&kr[b2_], 1);
        partr[br[b2_] + k2] = (unsigned char)(r & 255);
    }
}

// ---------------- pass 4: per-bucket CSR (off + srcw), all in LDS ----------------
__global__ __launch_bounds__(256) void k_bucket_col(const unsigned* __restrict__ partc,
        const int* __restrict__ coff, int* __restrict__ off, int* __restrict__ srcw) {
    __shared__ int cnt[256], sc[256], run[256];
    int b = blockIdx.x, t = threadIdx.x;
    cnt[t] = 0; run[t] = 0;
    __syncthreads();
    int s = coff[b], e = coff[b + 1];
    for (int i = s + t; i < e; i += 256)
        atomicAdd(&cnt[partc[i] >> 17], 1);
    __syncthreads();
    int v = cnt[t]; sc[t] = v; __syncthreads();
    for (int o = 1; o < 256; o <<= 1) {
        int a = (t >= o) ? sc[t - o] : 0;
        __syncthreads();
        sc[t] += a;
        __syncthreads();
    }
    int ex = sc[t] - v;
    __syncthreads();
    sc[t] = ex;
    __syncthreads();
    int n = (b << 8) + t;
    if (n < N_NODES) off[n] = s + ex;
    for (int i = s + t; i < e; i += 256) {
        unsigned p = partc[i];
        int c = p >> 17;
        int k = atomicAdd(&run[c], 1);
        srcw[s + sc[c] + k] = (int)(p & 0x1FFFFu);
    }
}

// ---------------- pass 5: per-bucket out-degree histogram -> dis ----------------
__global__ __launch_bounds__(256) void k_bucket_row(const unsigned char* __restrict__ partr,
        const int* __restrict__ roff, float* __restrict__ dis) {
    __shared__ int cnt[256];
    int b = blockIdx.x, t = threadIdx.x;
    cnt[t] = 0;
    __syncthreads();
    int s = roff[b], e = roff[b + 1];
    for (int i = s + t; i < e; i += 256) atomicAdd(&cnt[partr[i]], 1);
    __syncthreads();
    int n = (b << 8) + t;
    if (n < N_NODES) dis[n] = rsqrtf((float)(1 + cnt[t]));  // +1 self-loop
}

// ---------------- lin1: hs1b = bf16( dis[n] * (x W1^T + b1) ) ----------------
__global__ __launch_bounds__(256) void k_lin1(const float* __restrict__ x,
        const float* __restrict__ W1, const float* __restrict__ b1,
        const float* __restrict__ dis, unsigned* __restrict__ hs1b) {
    __shared__ float w1t[D_IN][H1F + 1];
    __shared__ float xs[8][D_IN];
    int tid = threadIdx.x;
    for (int idx = tid; idx < H1F * D_IN; idx += 256) {
        int f = idx >> 7, k = idx & 127;
        w1t[k][f] = W1[idx];
    }
    int nbase = blockIdx.x * 8;
    for (int idx = tid; idx < 8 * D_IN; idx += 256) {
        int nn = idx >> 7, k = idx & 127;
        int n = nbase + nn;
        xs[nn][k] = (n < N_NODES) ? x[(long long)n * D_IN + k] : 0.0f;
    }
    __syncthreads();
    int f = tid & 31, sub = tid >> 5;
    int n = nbase + sub;
    float acc = 0.f;
    #pragma unroll
    for (int k = 0; k < D_IN; ++k) acc += xs[sub][k] * w1t[k][f];
    float val = (n < N_NODES) ? dis[n] * (acc + b1[f]) : 0.f;
    float other = __shfl_xor(val, 1);
    if ((f & 1) == 0 && n < N_NODES)
        hs1b[n * 16 + (f >> 1)] = f2bf(val) | (f2bf(other) << 16);
}

// ---------------- gather1: hs2b = bf16( dis_c * relu( dis_c*(hs1_c + sum hs1_src) ) ) ----
__global__ __launch_bounds__(256) void k_gather1(const int* __restrict__ srcw,
        const int* __restrict__ off, const float* __restrict__ dis,
        const unsigned* __restrict__ hs, unsigned* __restrict__ out) {
    int lane = threadIdx.x & 63;
    int c = (blockIdx.x * 256 + threadIdx.x) >> 6;
    if (c >= N_NODES) return;
    int g = lane >> 4, lf = lane & 15;
    int s = off[c], e = off[c + 1];
    float a0 = 0.f, a1 = 0.f;
    if (g == 0) {
        unsigned su = hs[c * 16 + lf];
        a0 = bf2f(su & 0xffffu); a1 = bf2f(su >> 16);
    }
    int j = s + g;
    for (; j + 4 < e; j += 8) {
        int s0 = srcw[j], s1 = srcw[j + 4];
        unsigned u0 = hs[s0 * 16 + lf];
        unsigned u1 = hs[s1 * 16 + lf];
        a0 += bf2f(u0 & 0xffffu); a1 += bf2f(u0 >> 16);
        a0 += bf2f(u1 & 0xffffu); a1 += bf2f(u1 >> 16);
    }
    if (j < e) {
        unsigned u0 = hs[srcw[j] * 16 + lf];
        a0 += bf2f(u0 & 0xffffu); a1 += bf2f(u0 >> 16);
    }
    a0 += __shfl_xor(a0, 16); a0 += __shfl_xor(a0, 32);
    a1 += __shfl_xor(a1, 16); a1 += __shfl_xor(a1, 32);
    if (g == 0) {
        float dc = dis[c];
        float v0 = dc * fmaxf(dc * a0, 0.f);
        float v1 = dc * fmaxf(dc * a1, 0.f);
        out[c * 16 + lf] = f2bf(v0) | (f2bf(v1) << 16);
    }
}

// ---------------- gather2: G = dis_c*(hs2_c + sum hs2_src) [32 fp32], Sd = dis_c*(dis_c+sum dis_src)
__global__ __launch_bounds__(256) void k_gather2(const int* __restrict__ srcw,
        const int* __restrict__ off, const float* __restrict__ dis,
        const unsigned* __restrict__ hs, float* __restrict__ G,
        float* __restrict__ Sd) {
    int lane = threadIdx.x & 63;
    int c = (blockIdx.x * 256 + threadIdx.x) >> 6;
    if (c >= N_NODES) return;
    int g = lane >> 4, lf = lane & 15;
    int s = off[c], e = off[c + 1];
    float a0 = 0.f, a1 = 0.f, ad = 0.f;
    if (g == 0) {
        unsigned su = hs[c * 16 + lf];
        a0 = bf2f(su & 0xffffu); a1 = bf2f(su >> 16);
    }
    int j = s + g;
    for (; j + 4 < e; j += 8) {
        int s0 = srcw[j], s1 = srcw[j + 4];
        unsigned u0 = hs[s0 * 16 + lf];
        unsigned u1 = hs[s1 * 16 + lf];
        ad += dis[s0] + dis[s1];
        a0 += bf2f(u0 & 0xffffu); a1 += bf2f(u0 >> 16);
        a0 += bf2f(u1 & 0xffffu); a1 += bf2f(u1 >> 16);
    }
    if (j < e) {
        int s0 = srcw[j];
        unsigned u0 = hs[s0 * 16 + lf];
        ad += dis[s0];
        a0 += bf2f(u0 & 0xffffu); a1 += bf2f(u0 >> 16);
    }
    a0 += __shfl_xor(a0, 16); a0 += __shfl_xor(a0, 32);
    a1 += __shfl_xor(a1, 16); a1 += __shfl_xor(a1, 32);
    ad += __shfl_xor(ad, 16); ad += __shfl_xor(ad, 32);
    if (g == 0) {
        float dc = dis[c];
        float2 w; w.x = dc * a0; w.y = dc * a1;
        *(float2*)(&G[c * 32 + lf * 2]) = w;
        if (lf == 0) Sd[c] = dc * (dc + ad);
    }
}

// ---------------- counts via binary search on sorted batch ----------------
__global__ void k_counts_bs(const int* __restrict__ batch, float* counts) {
    int g = threadIdx.x;
    if (g >= N_GRAPHS) return;
    int lo = 0, hi = N_NODES;
    while (lo < hi) { int mid = (lo + hi) >> 1; if (batch[mid] < g) lo = mid + 1; else hi = mid; }
    int start = lo;
    hi = N_NODES;
    while (lo < hi) { int mid = (lo + hi) >> 1; if (batch[mid] < g + 1) lo = mid + 1; else hi = mid; }
    counts[g] = (float)(lo - start);
}

// ---------------- fused lin2 + relu + mean-pool accumulate ----------------
__global__ __launch_bounds__(256) void k_lin2pool(const float* __restrict__ G,
        const float* __restrict__ Sd, const float* __restrict__ W2,
        const float* __restrict__ b2, const int* __restrict__ batch,
        float* __restrict__ sums) {
    __shared__ float w2t[H1F][H2F + 1];
    int tid = threadIdx.x;
    for (int idx = tid; idx < H2F * H1F; idx += 256) {
        int fo = idx >> 5, k = idx & 31;
        w2t[k][fo] = W2[idx];
    }
    __syncthreads();
    int f = tid & 63, sub = tid >> 6;
    float bfv = b2[f];
    int n0 = blockIdx.x * 256;
    float acc = 0.f; int gcur = -1;
    for (int i = sub; i < 256; i += 4) {
        int n = n0 + i;
        if (n >= N_NODES) break;
        const float4* Gr = (const float4*)(&G[n * 32]);
        float d = Sd[n] * bfv;
        #pragma unroll
        for (int q = 0; q < 8; ++q) {
            float4 v = Gr[q];
            d += v.x * w2t[4 * q][f] + v.y * w2t[4 * q + 1][f]
               + v.z * w2t[4 * q + 2][f] + v.w * w2t[4 * q + 3][f];
        }
        d = fmaxf(d, 0.f);
        int gg = batch[n];
        if (gg != gcur) {
            if (gcur >= 0) atomicAdd(&sums[gcur * H2F + f], acc);
            acc = 0.f; gcur = gg;
        }
        acc += d;
    }
    if (gcur >= 0) atomicAdd(&sums[gcur * H2F + f], acc);
}

// ---------------- final: mean, linear, softmax ----------------
__global__ __launch_bounds__(1024) void k_final(const float* __restrict__ sums,
        const float* __restrict__ counts, const float* __restrict__ Wf,
        const float* __restrict__ bf, float* __restrict__ out) {
    __shared__ float l[N_GRAPHS * N_CLASSES];
    int tid = threadIdx.x;
    if (tid < N_GRAPHS * N_CLASSES) {
        int g = tid / N_CLASSES, c = tid % N_CLASSES;
        float cnt = fmaxf(counts[g], 1.0f);
        float acc = bf[c];
        for (int f = 0; f < H2F; ++f)
            acc += (sums[g * H2F + f] / cnt) * Wf[c * H2F + f];
        l[tid] = acc;
    }
    __syncthreads();
    if (tid < N_GRAPHS) {
        float m = -1e30f;
        for (int c = 0; c < N_CLASSES; ++c) m = fmaxf(m, l[tid * N_CLASSES + c]);
        float s = 0.f;
        float ex[N_CLASSES];
        for (int c = 0; c < N_CLASSES; ++c) { ex[c] = expf(l[tid * N_CLASSES + c] - m); s += ex[c]; }
        for (int c = 0; c < N_CLASSES; ++c) out[tid * N_CLASSES + c] = ex[c] / s;
    }
}

extern "C" void kernel_launch(void* const* d_in, const int* in_sizes, int n_in,
                              void* d_out, int out_size, void* d_ws, size_t ws_size,
                              hipStream_t stream) {
    const float* x     = (const float*)d_in[0];
    const int*   ei    = (const int*)d_in[1];
    const int*   batch = (const int*)d_in[2];
    const float* W1    = (const float*)d_in[3];
    const float* b1    = (const float*)d_in[4];
    const float* W2    = (const float*)d_in[5];
    const float* b2    = (const float*)d_in[6];
    const float* Wf    = (const float*)d_in[7];
    const float* bf    = (const float*)d_in[8];
    float* out = (float*)d_out;

    const int* row = ei;            // edge_index[0,:] (source)
    const int* col = ei + N_EDGES;  // edge_index[1,:] (dest)

    // workspace layout (int units)
    int* W = (int*)d_ws;
    int*           ccount = W + 0;         // 391 (pad 400)
    int*           rcount = W + 400;
    int*           coff   = W + 800;       // 392
    int*           roff   = W + 1200;
    int*           cpos   = W + 1600;
    int*           rpos   = W + 2000;
    int*           off    = W + 2400;      // 100001 -> next 102408
    int*           srcw   = W + 102408;    // 3.2M -> 3302408
    unsigned*      partc  = (unsigned*)(W + 3302408);  // 3.2M u32 -> 6502408
    float*         G      = (float*)(W + 3302408);     // alias partc (dead after bucket_col)
    unsigned char* partr  = (unsigned char*)(W + 6502408);  // 3.2M u8 = 800000 ints -> 7302408
    float*         dis    = (float*)(W + 7302408);     // 100000
    float*         Sd     = (float*)(W + 7402408);     // 100000
    unsigned*      hs1b   = (unsigned*)(W + 7502408);  // 1.6M u32 -> 9102408
    unsigned*      hs2b   = (unsigned*)(W + 9102408);  // 1.6M u32 -> 10702408
    float*         sums   = (float*)(W + 10702408);    // 4096
    float*         cnts   = (float*)(W + 10706504);    // 64
    // total ~42.8 MB

    // ---- CSR build via 2-pass radix partition ----
    k_zero2<<<1, 256, 0, stream>>>(ccount, rcount);
    k_coarse<<<NPB, 256, 0, stream>>>(row, col, ccount, rcount);
    k_cscan<<<1, 512, 0, stream>>>(ccount, rcount, coff, roff, cpos, rpos, sums, off);
    k_part<<<NPB, 256, 0, stream>>>(row, col, cpos, rpos, partc, partr);
    k_bucket_col<<<NBUCK, 256, 0, stream>>>(partc, coff, off, srcw);
    k_bucket_row<<<NBUCK, 256, 0, stream>>>(partr, roff, dis);

    // ---- layer 1 ----
    k_lin1<<<(N_NODES + 7) / 8, 256, 0, stream>>>(x, W1, b1, dis, hs1b);
    k_gather1<<<(N_NODES + 3) / 4, 256, 0, stream>>>(srcw, off, dis, hs1b, hs2b);

    // ---- layer 2 (aggregate in 32-dim, lin2 fused into pool) ----
    k_gather2<<<(N_NODES + 3) / 4, 256, 0, stream>>>(srcw, off, dis, hs2b, G, Sd);

    // ---- pooling + head ----
    k_counts_bs<<<1, 64, 0, stream>>>(batch, cnts);
    k_lin2pool<<<(N_NODES + 255) / 256, 256, 0, stream>>>(G, Sd, W2, b2, batch, sums);
    k_final<<<1, 640, 0, stream>>>(sums, cnts, Wf, bf, out);
}

// Round 8
// 376.503 us; speedup vs baseline: 1.0407x; 1.0407x over previous
//
#include <hip/hip_runtime.h>

#define N_NODES   100000
#define N_EDGES   3200000
#define D_IN      128
#define H1F       32
#define H2F       64
#define N_CLASSES 10
#define N_GRAPHS  64

#define NBUCK 391      // ceil(100000 / 256) buckets of 256 nodes
// coarse histogram pass
#define NPBC  1024
#define EPBC  (N_EDGES / NPBC)   // 3125 exact
// partition pass (LDS-staged)
#define EPB   6144
#define NPB   ((N_EDGES + EPB - 1) / EPB)   // 521

// bf16 helpers (RNE pack)
__device__ __forceinline__ unsigned f2bf(float f) {
    unsigned u = __float_as_uint(f);
    return (u + 0x7fffu + ((u >> 16) & 1u)) >> 16;
}
__device__ __forceinline__ float bf2f(unsigned h) {
    return __uint_as_float(h << 16);
}

// ---------------- tiny zero for bucket counters ----------------
__global__ void k_zero2(int* ccount, int* rcount) {
    int t = threadIdx.x;
    for (int i = t; i < NBUCK; i += 256) { ccount[i] = 0; rcount[i] = 0; }
}

// ---------------- pass 1: coarse bucket histograms (col and row) ----------------
__global__ __launch_bounds__(256) void k_coarse(const int* __restrict__ row,
        const int* __restrict__ col, int* ccount, int* rcount) {
    __shared__ int ch[NBUCK], rh[NBUCK];
    int t = threadIdx.x;
    for (int i = t; i < NBUCK; i += 256) { ch[i] = 0; rh[i] = 0; }
    __syncthreads();
    int s = blockIdx.x * EPBC, e = s + EPBC;
    for (int i = s + t; i < e; i += 256) {
        atomicAdd(&ch[col[i] >> 8], 1);
        atomicAdd(&rh[row[i] >> 8], 1);
    }
    __syncthreads();
    for (int i = t; i < NBUCK; i += 256) {
        if (ch[i]) atomicAdd(&ccount[i], ch[i]);
        if (rh[i]) atomicAdd(&rcount[i], rh[i]);
    }
}

// ---------------- pass 2: scan bucket counts -> offsets; misc init ----------------
__global__ __launch_bounds__(512) void k_cscan(const int* __restrict__ ccount,
        const int* __restrict__ rcount, int* coff, int* roff, int* cpos, int* rpos,
        float* sums, int* off) {
    __shared__ int sc[512], sr[512];
    int t = threadIdx.x;
    int vc = (t < NBUCK) ? ccount[t] : 0;
    int vr = (t < NBUCK) ? rcount[t] : 0;
    sc[t] = vc; sr[t] = vr; __syncthreads();
    for (int o = 1; o < 512; o <<= 1) {
        int a = (t >= o) ? sc[t - o] : 0;
        int b = (t >= o) ? sr[t - o] : 0;
        __syncthreads();
        sc[t] += a; sr[t] += b;
        __syncthreads();
    }
    if (t < NBUCK) {
        int ce = sc[t] - vc, re = sr[t] - vr;
        coff[t] = ce; cpos[t] = ce;
        roff[t] = re; rpos[t] = re;
    }
    if (t == 0) { coff[NBUCK] = N_EDGES; roff[NBUCK] = N_EDGES; off[N_NODES] = N_EDGES; }
    for (int i = t; i < N_GRAPHS * H2F; i += 512) sums[i] = 0.f;
}

// ---------------- pass 3: LDS-staged partition (coalesced write-out) ----------------
__global__ __launch_bounds__(256) void k_part(const int* __restrict__ row,
        const int* __restrict__ col, int* cpos, int* rpos,
        unsigned* __restrict__ partc, unsigned char* __restrict__ partr) {
    __shared__ int sc[512], sr[512];            // histogram -> inclusive scan
    __shared__ int posc[NBUCK], posr[NBUCK];    // scatter cursors (local)
    __shared__ int basec[NBUCK], baser[NBUCK];  // global bases
    __shared__ unsigned stagc[EPB];             // 24.6 KB
    __shared__ unsigned char stagr[EPB];        // 6.1 KB
    int t = threadIdx.x;
    sc[t] = 0; sc[t + 256] = 0; sr[t] = 0; sr[t + 256] = 0;
    __syncthreads();
    int s = blockIdx.x * EPB;
    int e = min(s + EPB, N_EDGES);
    // phase A: local histograms
    for (int i = s + t; i < e; i += 256) {
        atomicAdd(&sc[col[i] >> 8], 1);
        atomicAdd(&sr[row[i] >> 8], 1);
    }
    __syncthreads();
    // phase B: inclusive scan over 512 (2 slots/thread)
    for (int o = 1; o < 512; o <<= 1) {
        int a0 = (t >= o) ? sc[t - o] : 0;
        int a1 = sc[t + 256 - o];
        int b0 = (t >= o) ? sr[t - o] : 0;
        int b1 = sr[t + 256 - o];
        __syncthreads();
        sc[t] += a0; sc[t + 256] += a1;
        sr[t] += b0; sr[t + 256] += b1;
        __syncthreads();
    }
    // phase C: per-bucket local starts + global reservations
    for (int b = t; b < NBUCK; b += 256) {
        int cc = sc[b] - (b ? sc[b - 1] : 0);
        int rc = sr[b] - (b ? sr[b - 1] : 0);
        posc[b] = sc[b] - cc;
        posr[b] = sr[b] - rc;
        basec[b] = cc ? atomicAdd(&cpos[b], cc) : 0;
        baser[b] = rc ? atomicAdd(&rpos[b], rc) : 0;
    }
    __syncthreads();
    // phase D: scatter into LDS staging (edge re-read is L2-hot)
    for (int i = s + t; i < e; i += 256) {
        int c = col[i], r = row[i];
        int b = c >> 8;
        int p = atomicAdd(&posc[b], 1);
        stagc[p] = ((unsigned)(c & 255) << 17) | (unsigned)r;  // row < 2^17
        int b2 = r >> 8;
        int p2 = atomicAdd(&posr[b2], 1);
        stagr[p2] = (unsigned char)(r & 255);
    }
    __syncthreads();
    // phase E: sorted write-out; bucket of position i via binary search on sc/sr
    int nloc = e - s;
    for (int i = t; i < nloc; i += 256) {
        int lo = 0, hi = NBUCK - 1;
        while (lo < hi) { int m = (lo + hi) >> 1; if (sc[m] > i) hi = m; else lo = m + 1; }
        int start = lo ? sc[lo - 1] : 0;
        partc[basec[lo] + (i - start)] = stagc[i];
    }
    for (int i = t; i < nloc; i += 256) {
        int lo = 0, hi = NBUCK - 1;
        while (lo < hi) { int m = (lo + hi) >> 1; if (sr[m] > i) hi = m; else lo = m + 1; }
        int start = lo ? sr[lo - 1] : 0;
        partr[baser[lo] + (i - start)] = stagr[i];
    }
}

// ---------------- pass 4: per-bucket CSR (off + srcw), all in LDS ----------------
__global__ __launch_bounds__(256) void k_bucket_col(const unsigned* __restrict__ partc,
        const int* __restrict__ coff, int* __restrict__ off, int* __restrict__ srcw) {
    __shared__ int cnt[256], sc[256], run[256];
    int b = blockIdx.x, t = threadIdx.x;
    cnt[t] = 0; run[t] = 0;
    __syncthreads();
    int s = coff[b], e = coff[b + 1];
    for (int i = s + t; i < e; i += 256)
        atomicAdd(&cnt[partc[i] >> 17], 1);
    __syncthreads();
    int v = cnt[t]; sc[t] = v; __syncthreads();
    for (int o = 1; o < 256; o <<= 1) {
        int a = (t >= o) ? sc[t - o] : 0;
        __syncthreads();
        sc[t] += a;
        __syncthreads();
    }
    int ex = sc[t] - v;
    __syncthreads();
    sc[t] = ex;
    __syncthreads();
    int n = (b << 8) + t;
    if (n < N_NODES) off[n] = s + ex;
    for (int i = s + t; i < e; i += 256) {
        unsigned p = partc[i];
        int c = p >> 17;
        int k = atomicAdd(&run[c], 1);
        srcw[s + sc[c] + k] = (int)(p & 0x1FFFFu);
    }
}

// ---------------- pass 5: per-bucket out-degree histogram -> dis ----------------
__global__ __launch_bounds__(256) void k_bucket_row(const unsigned char* __restrict__ partr,
        const int* __restrict__ roff, float* __restrict__ dis) {
    __shared__ int cnt[256];
    int b = blockIdx.x, t = threadIdx.x;
    cnt[t] = 0;
    __syncthreads();
    int s = roff[b], e = roff[b + 1];
    for (int i = s + t; i < e; i += 256) atomicAdd(&cnt[partr[i]], 1);
    __syncthreads();
    int n = (b << 8) + t;
    if (n < N_NODES) dis[n] = rsqrtf((float)(1 + cnt[t]));  // +1 self-loop
}

// ---------------- lin1: hs1b = bf16( dis[n] * (x W1^T + b1) ) ----------------
__global__ __launch_bounds__(256) void k_lin1(const float* __restrict__ x,
        const float* __restrict__ W1, const float* __restrict__ b1,
        const float* __restrict__ dis, unsigned* __restrict__ hs1b) {
    __shared__ float w1t[D_IN][H1F + 1];
    __shared__ float xs[8][D_IN];
    int tid = threadIdx.x;
    for (int idx = tid; idx < H1F * D_IN; idx += 256) {
        int f = idx >> 7, k = idx & 127;
        w1t[k][f] = W1[idx];
    }
    int nbase = blockIdx.x * 8;
    for (int idx = tid; idx < 8 * D_IN; idx += 256) {
        int nn = idx >> 7, k = idx & 127;
        int n = nbase + nn;
        xs[nn][k] = (n < N_NODES) ? x[(long long)n * D_IN + k] : 0.0f;
    }
    __syncthreads();
    int f = tid & 31, sub = tid >> 5;
    int n = nbase + sub;
    float acc = 0.f;
    #pragma unroll
    for (int k = 0; k < D_IN; ++k) acc += xs[sub][k] * w1t[k][f];
    float val = (n < N_NODES) ? dis[n] * (acc + b1[f]) : 0.f;
    float other = __shfl_xor(val, 1);
    if ((f & 1) == 0 && n < N_NODES)
        hs1b[n * 16 + (f >> 1)] = f2bf(val) | (f2bf(other) << 16);
}

// ---------------- gather1: hs2b = bf16( dis_c * relu( dis_c*(hs1_c + sum hs1_src) ) ) ----
__global__ __launch_bounds__(256) void k_gather1(const int* __restrict__ srcw,
        const int* __restrict__ off, const float* __restrict__ dis,
        const unsigned* __restrict__ hs, unsigned* __restrict__ out) {
    int lane = threadIdx.x & 63;
    int c = (blockIdx.x * 256 + threadIdx.x) >> 6;
    if (c >= N_NODES) return;
    int g = lane >> 4, lf = lane & 15;
    int s = off[c], e = off[c + 1];
    float a0 = 0.f, a1 = 0.f;
    if (g == 0) {
        unsigned su = hs[c * 16 + lf];
        a0 = bf2f(su & 0xffffu); a1 = bf2f(su >> 16);
    }
    int j = s + g;
    for (; j + 4 < e; j += 8) {
        int s0 = srcw[j], s1 = srcw[j + 4];
        unsigned u0 = hs[s0 * 16 + lf];
        unsigned u1 = hs[s1 * 16 + lf];
        a0 += bf2f(u0 & 0xffffu); a1 += bf2f(u0 >> 16);
        a0 += bf2f(u1 & 0xffffu); a1 += bf2f(u1 >> 16);
    }
    if (j < e) {
        unsigned u0 = hs[srcw[j] * 16 + lf];
        a0 += bf2f(u0 & 0xffffu); a1 += bf2f(u0 >> 16);
    }
    a0 += __shfl_xor(a0, 16); a0 += __shfl_xor(a0, 32);
    a1 += __shfl_xor(a1, 16); a1 += __shfl_xor(a1, 32);
    if (g == 0) {
        float dc = dis[c];
        float v0 = dc * fmaxf(dc * a0, 0.f);
        float v1 = dc * fmaxf(dc * a1, 0.f);
        out[c * 16 + lf] = f2bf(v0) | (f2bf(v1) << 16);
    }
}

// ---------------- gather2: G = dis_c*(hs2_c + sum hs2_src) [32 fp32], Sd = dis_c*(dis_c+sum dis_src)
__global__ __launch_bounds__(256) void k_gather2(const int* __restrict__ srcw,
        const int* __restrict__ off, const float* __restrict__ dis,
        const unsigned* __restrict__ hs, float* __restrict__ G,
        float* __restrict__ Sd) {
    int lane = threadIdx.x & 63;
    int c = (blockIdx.x * 256 + threadIdx.x) >> 6;
    if (c >= N_NODES) return;
    int g = lane >> 4, lf = lane & 15;
    int s = off[c], e = off[c + 1];
    float a0 = 0.f, a1 = 0.f, ad = 0.f;
    if (g == 0) {
        unsigned su = hs[c * 16 + lf];
        a0 = bf2f(su & 0xffffu); a1 = bf2f(su >> 16);
    }
    int j = s + g;
    for (; j + 4 < e; j += 8) {
        int s0 = srcw[j], s1 = srcw[j + 4];
        unsigned u0 = hs[s0 * 16 + lf];
        unsigned u1 = hs[s1 * 16 + lf];
        ad += dis[s0] + dis[s1];
        a0 += bf2f(u0 & 0xffffu); a1 += bf2f(u0 >> 16);
        a0 += bf2f(u1 & 0xffffu); a1 += bf2f(u1 >> 16);
    }
    if (j < e) {
        int s0 = srcw[j];
        unsigned u0 = hs[s0 * 16 + lf];
        ad += dis[s0];
        a0 += bf2f(u0 & 0xffffu); a1 += bf2f(u0 >> 16);
    }
    a0 += __shfl_xor(a0, 16); a0 += __shfl_xor(a0, 32);
    a1 += __shfl_xor(a1, 16); a1 += __shfl_xor(a1, 32);
    ad += __shfl_xor(ad, 16); ad += __shfl_xor(ad, 32);
    if (g == 0) {
        float dc = dis[c];
        float2 w; w.x = dc * a0; w.y = dc * a1;
        *(float2*)(&G[c * 32 + lf * 2]) = w;
        if (lf == 0) Sd[c] = dc * (dc + ad);
    }
}

// ---------------- counts via binary search on sorted batch ----------------
__global__ void k_counts_bs(const int* __restrict__ batch, float* counts) {
    int g = threadIdx.x;
    if (g >= N_GRAPHS) return;
    int lo = 0, hi = N_NODES;
    while (lo < hi) { int mid = (lo + hi) >> 1; if (batch[mid] < g) lo = mid + 1; else hi = mid; }
    int start = lo;
    hi = N_NODES;
    while (lo < hi) { int mid = (lo + hi) >> 1; if (batch[mid] < g + 1) lo = mid + 1; else hi = mid; }
    counts[g] = (float)(lo - start);
}

// ---------------- fused lin2 + relu + mean-pool accumulate ----------------
__global__ __launch_bounds__(256) void k_lin2pool(const float* __restrict__ G,
        const float* __restrict__ Sd, const float* __restrict__ W2,
        const float* __restrict__ b2, const int* __restrict__ batch,
        float* __restrict__ sums) {
    __shared__ float w2t[H1F][H2F + 1];
    int tid = threadIdx.x;
    for (int idx = tid; idx < H2F * H1F; idx += 256) {
        int fo = idx >> 5, k = idx & 31;
        w2t[k][fo] = W2[idx];
    }
    __syncthreads();
    int f = tid & 63, sub = tid >> 6;
    float bfv = b2[f];
    int n0 = blockIdx.x * 256;
    float acc = 0.f; int gcur = -1;
    for (int i = sub; i < 256; i += 4) {
        int n = n0 + i;
        if (n >= N_NODES) break;
        const float4* Gr = (const float4*)(&G[n * 32]);
        float d = Sd[n] * bfv;
        #pragma unroll
        for (int q = 0; q < 8; ++q) {
            float4 v = Gr[q];
            d += v.x * w2t[4 * q][f] + v.y * w2t[4 * q + 1][f]
               + v.z * w2t[4 * q + 2][f] + v.w * w2t[4 * q + 3][f];
        }
        d = fmaxf(d, 0.f);
        int gg = batch[n];
        if (gg != gcur) {
            if (gcur >= 0) atomicAdd(&sums[gcur * H2F + f], acc);
            acc = 0.f; gcur = gg;
        }
        acc += d;
    }
    if (gcur >= 0) atomicAdd(&sums[gcur * H2F + f], acc);
}

// ---------------- final: mean, linear, softmax ----------------
__global__ __launch_bounds__(1024) void k_final(const float* __restrict__ sums,
        const float* __restrict__ counts, const float* __restrict__ Wf,
        const float* __restrict__ bf, float* __restrict__ out) {
    __shared__ float l[N_GRAPHS * N_CLASSES];
    int tid = threadIdx.x;
    if (tid < N_GRAPHS * N_CLASSES) {
        int g = tid / N_CLASSES, c = tid % N_CLASSES;
        float cnt = fmaxf(counts[g], 1.0f);
        float acc = bf[c];
        for (int f = 0; f < H2F; ++f)
            acc += (sums[g * H2F + f] / cnt) * Wf[c * H2F + f];
        l[tid] = acc;
    }
    __syncthreads();
    if (tid < N_GRAPHS) {
        float m = -1e30f;
        for (int c = 0; c < N_CLASSES; ++c) m = fmaxf(m, l[tid * N_CLASSES + c]);
        float s = 0.f;
        float ex[N_CLASSES];
        for (int c = 0; c < N_CLASSES; ++c) { ex[c] = expf(l[tid * N_CLASSES + c] - m); s += ex[c]; }
        for (int c = 0; c < N_CLASSES; ++c) out[tid * N_CLASSES + c] = ex[c] / s;
    }
}

extern "C" void kernel_launch(void* const* d_in, const int* in_sizes, int n_in,
                              void* d_out, int out_size, void* d_ws, size_t ws_size,
                              hipStream_t stream) {
    const float* x     = (const float*)d_in[0];
    const int*   ei    = (const int*)d_in[1];
    const int*   batch = (const int*)d_in[2];
    const float* W1    = (const float*)d_in[3];
    const float* b1    = (const float*)d_in[4];
    const float* W2    = (const float*)d_in[5];
    const float* b2    = (const float*)d_in[6];
    const float* Wf    = (const float*)d_in[7];
    const float* bf    = (const float*)d_in[8];
    float* out = (float*)d_out;

    const int* row = ei;            // edge_index[0,:] (source)
    const int* col = ei + N_EDGES;  // edge_index[1,:] (dest)

    // workspace layout (int units)
    int* W = (int*)d_ws;
    int*           ccount = W + 0;         // 391 (pad 400)
    int*           rcount = W + 400;
    int*           coff   = W + 800;       // 392
    int*           roff   = W + 1200;
    int*           cpos   = W + 1600;
    int*           rpos   = W + 2000;
    int*           off    = W + 2400;      // 100001 -> next 102408
    int*           srcw   = W + 102408;    // 3.2M -> 3302408
    unsigned*      partc  = (unsigned*)(W + 3302408);  // 3.2M u32 -> 6502408
    float*         G      = (float*)(W + 3302408);     // alias partc (dead after bucket_col)
    unsigned char* partr  = (unsigned char*)(W + 6502408);  // 3.2M u8 = 800000 ints -> 7302408
    float*         dis    = (float*)(W + 7302408);     // 100000
    float*         Sd     = (float*)(W + 7402408);     // 100000
    unsigned*      hs1b   = (unsigned*)(W + 7502408);  // 1.6M u32 -> 9102408
    unsigned*      hs2b   = (unsigned*)(W + 9102408);  // 1.6M u32 -> 10702408
    float*         sums   = (float*)(W + 10702408);    // 4096
    float*         cnts   = (float*)(W + 10706504);    // 64
    // total ~42.8 MB

    // ---- CSR build via 2-pass radix partition ----
    k_zero2<<<1, 256, 0, stream>>>(ccount, rcount);
    k_coarse<<<NPBC, 256, 0, stream>>>(row, col, ccount, rcount);
    k_cscan<<<1, 512, 0, stream>>>(ccount, rcount, coff, roff, cpos, rpos, sums, off);
    k_part<<<NPB, 256, 0, stream>>>(row, col, cpos, rpos, partc, partr);
    k_bucket_col<<<NBUCK, 256, 0, stream>>>(partc, coff, off, srcw);
    k_bucket_row<<<NBUCK, 256, 0, stream>>>(partr, roff, dis);

    // ---- layer 1 ----
    k_lin1<<<(N_NODES + 7) / 8, 256, 0, stream>>>(x, W1, b1, dis, hs1b);
    k_gather1<<<(N_NODES + 3) / 4, 256, 0, stream>>>(srcw, off, dis, hs1b, hs2b);

    // ---- layer 2 (aggregate in 32-dim, lin2 fused into pool) ----
    k_gather2<<<(N_NODES + 3) / 4, 256, 0, stream>>>(srcw, off, dis, hs2b, G, Sd);

    // ---- pooling + head ----
    k_counts_bs<<<1, 64, 0, stream>>>(batch, cnts);
    k_lin2pool<<<(N_NODES + 255) / 256, 256, 0, stream>>>(G, Sd, W2, b2, batch, sums);
    k_final<<<1, 640, 0, stream>>>(sums, cnts, Wf, bf, out);
}

// Round 9
// 358.518 us; speedup vs baseline: 1.0929x; 1.0502x over previous
//
#include <hip/hip_runtime.h>

#define N_NODES   100000
#define N_EDGES   3200000
#define D_IN      128
#define H1F       32
#define H2F       64
#define N_CLASSES 10
#define N_GRAPHS  64

#define NBUCK 391      // ceil(100000 / 256) buckets of 256 nodes
// coarse histogram pass
#define NPBC  1024
#define EPBC  (N_EDGES / NPBC)   // 3125 exact
// partition pass (LDS-staged)
#define EPB   6144
#define NPB   ((N_EDGES + EPB - 1) / EPB)   // 521

// bf16 helpers (RNE pack)
__device__ __forceinline__ unsigned f2bf(float f) {
    unsigned u = __float_as_uint(f);
    return (u + 0x7fffu + ((u >> 16) & 1u)) >> 16;
}
__device__ __forceinline__ float bf2f(unsigned h) {
    return __uint_as_float(h << 16);
}

// ---------------- tiny zero for bucket counters ----------------
__global__ void k_zero2(int* ccount, int* rcount) {
    int t = threadIdx.x;
    for (int i = t; i < NBUCK; i += 256) { ccount[i] = 0; rcount[i] = 0; }
}

// ---------------- pass 1: coarse bucket histograms (col and row) ----------------
__global__ __launch_bounds__(256) void k_coarse(const int* __restrict__ row,
        const int* __restrict__ col, int* ccount, int* rcount) {
    __shared__ int ch[NBUCK], rh[NBUCK];
    int t = threadIdx.x;
    for (int i = t; i < NBUCK; i += 256) { ch[i] = 0; rh[i] = 0; }
    __syncthreads();
    int s = blockIdx.x * EPBC, e = s + EPBC;
    for (int i = s + t; i < e; i += 256) {
        atomicAdd(&ch[col[i] >> 8], 1);
        atomicAdd(&rh[row[i] >> 8], 1);
    }
    __syncthreads();
    for (int i = t; i < NBUCK; i += 256) {
        if (ch[i]) atomicAdd(&ccount[i], ch[i]);
        if (rh[i]) atomicAdd(&rcount[i], rh[i]);
    }
}

// ---------------- pass 2: scan bucket counts -> offsets; misc init ----------------
__global__ __launch_bounds__(512) void k_cscan(const int* __restrict__ ccount,
        const int* __restrict__ rcount, int* coff, int* roff, int* cpos, int* rpos,
        float* sums, int* off) {
    __shared__ int sc[512], sr[512];
    int t = threadIdx.x;
    int vc = (t < NBUCK) ? ccount[t] : 0;
    int vr = (t < NBUCK) ? rcount[t] : 0;
    sc[t] = vc; sr[t] = vr; __syncthreads();
    for (int o = 1; o < 512; o <<= 1) {
        int a = (t >= o) ? sc[t - o] : 0;
        int b = (t >= o) ? sr[t - o] : 0;
        __syncthreads();
        sc[t] += a; sr[t] += b;
        __syncthreads();
    }
    if (t < NBUCK) {
        int ce = sc[t] - vc, re = sr[t] - vr;
        coff[t] = ce; cpos[t] = ce;
        roff[t] = re; rpos[t] = re;
    }
    if (t == 0) { coff[NBUCK] = N_EDGES; roff[NBUCK] = N_EDGES; off[N_NODES] = N_EDGES; }
    for (int i = t; i < N_GRAPHS * H2F; i += 512) sums[i] = 0.f;
}

// ---------------- pass 3: LDS-staged partition (coalesced write-out) ----------------
__global__ __launch_bounds__(256) void k_part(const int* __restrict__ row,
        const int* __restrict__ col, int* cpos, int* rpos,
        unsigned* __restrict__ partc, unsigned char* __restrict__ partr) {
    __shared__ int sc[512], sr[512];            // histogram -> inclusive scan
    __shared__ int posc[NBUCK], posr[NBUCK];    // scatter cursors (local)
    __shared__ int basec[NBUCK], baser[NBUCK];  // global bases
    __shared__ unsigned stagc[EPB];             // 24.6 KB
    __shared__ unsigned char stagr[EPB];        // 6.1 KB
    int t = threadIdx.x;
    sc[t] = 0; sc[t + 256] = 0; sr[t] = 0; sr[t + 256] = 0;
    __syncthreads();
    int s = blockIdx.x * EPB;
    int e = min(s + EPB, N_EDGES);
    // phase A: local histograms
    for (int i = s + t; i < e; i += 256) {
        atomicAdd(&sc[col[i] >> 8], 1);
        atomicAdd(&sr[row[i] >> 8], 1);
    }
    __syncthreads();
    // phase B: inclusive scan over 512 (2 slots/thread)
    for (int o = 1; o < 512; o <<= 1) {
        int a0 = (t >= o) ? sc[t - o] : 0;
        int a1 = sc[t + 256 - o];
        int b0 = (t >= o) ? sr[t - o] : 0;
        int b1 = sr[t + 256 - o];
        __syncthreads();
        sc[t] += a0; sc[t + 256] += a1;
        sr[t] += b0; sr[t + 256] += b1;
        __syncthreads();
    }
    // phase C: per-bucket local starts + global reservations
    for (int b = t; b < NBUCK; b += 256) {
        int cc = sc[b] - (b ? sc[b - 1] : 0);
        int rc = sr[b] - (b ? sr[b - 1] : 0);
        posc[b] = sc[b] - cc;
        posr[b] = sr[b] - rc;
        basec[b] = cc ? atomicAdd(&cpos[b], cc) : 0;
        baser[b] = rc ? atomicAdd(&rpos[b], rc) : 0;
    }
    __syncthreads();
    // phase D: scatter into LDS staging (edge re-read is L2-hot)
    for (int i = s + t; i < e; i += 256) {
        int c = col[i], r = row[i];
        int b = c >> 8;
        int p = atomicAdd(&posc[b], 1);
        stagc[p] = ((unsigned)(c & 255) << 17) | (unsigned)r;  // row < 2^17
        int b2 = r >> 8;
        int p2 = atomicAdd(&posr[b2], 1);
        stagr[p2] = (unsigned char)(r & 255);
    }
    __syncthreads();
    // phase E: sorted write-out; bucket of position i via binary search on sc/sr
    int nloc = e - s;
    for (int i = t; i < nloc; i += 256) {
        int lo = 0, hi = NBUCK - 1;
        while (lo < hi) { int m = (lo + hi) >> 1; if (sc[m] > i) hi = m; else lo = m + 1; }
        int start = lo ? sc[lo - 1] : 0;
        partc[basec[lo] + (i - start)] = stagc[i];
    }
    for (int i = t; i < nloc; i += 256) {
        int lo = 0, hi = NBUCK - 1;
        while (lo < hi) { int m = (lo + hi) >> 1; if (sr[m] > i) hi = m; else lo = m + 1; }
        int start = lo ? sr[lo - 1] : 0;
        partr[baser[lo] + (i - start)] = stagr[i];
    }
}

// ---------------- pass 4: per-bucket CSR (off + srcw), all in LDS ----------------
__global__ __launch_bounds__(256) void k_bucket_col(const unsigned* __restrict__ partc,
        const int* __restrict__ coff, int* __restrict__ off, int* __restrict__ srcw) {
    __shared__ int cnt[256], sc[256], run[256];
    int b = blockIdx.x, t = threadIdx.x;
    cnt[t] = 0; run[t] = 0;
    __syncthreads();
    int s = coff[b], e = coff[b + 1];
    for (int i = s + t; i < e; i += 256)
        atomicAdd(&cnt[partc[i] >> 17], 1);
    __syncthreads();
    int v = cnt[t]; sc[t] = v; __syncthreads();
    for (int o = 1; o < 256; o <<= 1) {
        int a = (t >= o) ? sc[t - o] : 0;
        __syncthreads();
        sc[t] += a;
        __syncthreads();
    }
    int ex = sc[t] - v;
    __syncthreads();
    sc[t] = ex;
    __syncthreads();
    int n = (b << 8) + t;
    if (n < N_NODES) off[n] = s + ex;
    for (int i = s + t; i < e; i += 256) {
        unsigned p = partc[i];
        int c = p >> 17;
        int k = atomicAdd(&run[c], 1);
        srcw[s + sc[c] + k] = (int)(p & 0x1FFFFu);
    }
}

// ---------------- pass 5: per-bucket out-degree histogram -> dis ----------------
__global__ __launch_bounds__(256) void k_bucket_row(const unsigned char* __restrict__ partr,
        const int* __restrict__ roff, float* __restrict__ dis) {
    __shared__ int cnt[256];
    int b = blockIdx.x, t = threadIdx.x;
    cnt[t] = 0;
    __syncthreads();
    int s = roff[b], e = roff[b + 1];
    for (int i = s + t; i < e; i += 256) atomicAdd(&cnt[partr[i]], 1);
    __syncthreads();
    int n = (b << 8) + t;
    if (n < N_NODES) dis[n] = rsqrtf((float)(1 + cnt[t]));  // +1 self-loop
}

// ---------------- lin1: hs1b = bf16( dis[n] * (x W1^T + b1) ) ----------------
__global__ __launch_bounds__(256) void k_lin1(const float* __restrict__ x,
        const float* __restrict__ W1, const float* __restrict__ b1,
        const float* __restrict__ dis, unsigned* __restrict__ hs1b) {
    __shared__ float w1t[D_IN][H1F + 1];
    __shared__ float xs[8][D_IN];
    int tid = threadIdx.x;
    for (int idx = tid; idx < H1F * D_IN; idx += 256) {
        int f = idx >> 7, k = idx & 127;
        w1t[k][f] = W1[idx];
    }
    int nbase = blockIdx.x * 8;
    for (int idx = tid; idx < 8 * D_IN; idx += 256) {
        int nn = idx >> 7, k = idx & 127;
        int n = nbase + nn;
        xs[nn][k] = (n < N_NODES) ? x[(long long)n * D_IN + k] : 0.0f;
    }
    __syncthreads();
    int f = tid & 31, sub = tid >> 5;
    int n = nbase + sub;
    float acc = 0.f;
    #pragma unroll
    for (int k = 0; k < D_IN; ++k) acc += xs[sub][k] * w1t[k][f];
    float val = (n < N_NODES) ? dis[n] * (acc + b1[f]) : 0.f;
    float other = __shfl_xor(val, 1);
    if ((f & 1) == 0 && n < N_NODES)
        hs1b[n * 16 + (f >> 1)] = f2bf(val) | (f2bf(other) << 16);
}

// ---------------- gather1: hs2b = bf16( dis_c * relu( dis_c*(hs1_c + sum hs1_src) ) ) ----
// one wave per node; 8 groups of 8 lanes, each group one edge (uint2/lane = 64B row);
// 2-way unroll => 16 edge-gathers in flight per wave
__global__ __launch_bounds__(256) void k_gather1(const int* __restrict__ srcw,
        const int* __restrict__ off, const float* __restrict__ dis,
        const unsigned* __restrict__ hs, unsigned* __restrict__ out) {
    int lane = threadIdx.x & 63;
    int c = (blockIdx.x * 256 + threadIdx.x) >> 6;
    if (c >= N_NODES) return;
    int e8 = lane >> 3, l8 = lane & 7;
    int s = off[c], e = off[c + 1];
    float a0 = 0.f, a1 = 0.f, a2 = 0.f, a3 = 0.f;
    if (e8 == 0) {
        uint2 u = ((const uint2*)(hs + c * 16))[l8];
        a0 = bf2f(u.x & 0xffffu); a1 = bf2f(u.x >> 16);
        a2 = bf2f(u.y & 0xffffu); a3 = bf2f(u.y >> 16);
    }
    int j = s + e8;
    for (; j + 8 < e; j += 16) {
        int s0 = srcw[j], s1 = srcw[j + 8];
        uint2 u0 = ((const uint2*)(hs + s0 * 16))[l8];
        uint2 u1 = ((const uint2*)(hs + s1 * 16))[l8];
        a0 += bf2f(u0.x & 0xffffu); a1 += bf2f(u0.x >> 16);
        a2 += bf2f(u0.y & 0xffffu); a3 += bf2f(u0.y >> 16);
        a0 += bf2f(u1.x & 0xffffu); a1 += bf2f(u1.x >> 16);
        a2 += bf2f(u1.y & 0xffffu); a3 += bf2f(u1.y >> 16);
    }
    if (j < e) {
        uint2 u0 = ((const uint2*)(hs + srcw[j] * 16))[l8];
        a0 += bf2f(u0.x & 0xffffu); a1 += bf2f(u0.x >> 16);
        a2 += bf2f(u0.y & 0xffffu); a3 += bf2f(u0.y >> 16);
    }
    // reduce across the 8 groups (lane bits 3,4,5)
    a0 += __shfl_xor(a0, 8);  a1 += __shfl_xor(a1, 8);
    a2 += __shfl_xor(a2, 8);  a3 += __shfl_xor(a3, 8);
    a0 += __shfl_xor(a0, 16); a1 += __shfl_xor(a1, 16);
    a2 += __shfl_xor(a2, 16); a3 += __shfl_xor(a3, 16);
    a0 += __shfl_xor(a0, 32); a1 += __shfl_xor(a1, 32);
    a2 += __shfl_xor(a2, 32); a3 += __shfl_xor(a3, 32);
    if (e8 == 0) {
        float dc = dis[c];
        uint2 w;
        w.x = f2bf(dc * fmaxf(dc * a0, 0.f)) | (f2bf(dc * fmaxf(dc * a1, 0.f)) << 16);
        w.y = f2bf(dc * fmaxf(dc * a2, 0.f)) | (f2bf(dc * fmaxf(dc * a3, 0.f)) << 16);
        ((uint2*)(out + c * 16))[l8] = w;
    }
}

// ---------------- gather2: G = dis_c*(hs2_c + sum hs2_src) [32 fp32], Sd = dis_c*(dis_c+sum dis_src)
__global__ __launch_bounds__(256) void k_gather2(const int* __restrict__ srcw,
        const int* __restrict__ off, const float* __restrict__ dis,
        const unsigned* __restrict__ hs, float* __restrict__ G,
        float* __restrict__ Sd) {
    int lane = threadIdx.x & 63;
    int c = (blockIdx.x * 256 + threadIdx.x) >> 6;
    if (c >= N_NODES) return;
    int e8 = lane >> 3, l8 = lane & 7;
    int s = off[c], e = off[c + 1];
    float a0 = 0.f, a1 = 0.f, a2 = 0.f, a3 = 0.f, ad = 0.f;
    if (e8 == 0) {
        uint2 u = ((const uint2*)(hs + c * 16))[l8];
        a0 = bf2f(u.x & 0xffffu); a1 = bf2f(u.x >> 16);
        a2 = bf2f(u.y & 0xffffu); a3 = bf2f(u.y >> 16);
    }
    int j = s + e8;
    for (; j + 8 < e; j += 16) {
        int s0 = srcw[j], s1 = srcw[j + 8];
        uint2 u0 = ((const uint2*)(hs + s0 * 16))[l8];
        uint2 u1 = ((const uint2*)(hs + s1 * 16))[l8];
        if (l8 == 0) ad += dis[s0] + dis[s1];
        a0 += bf2f(u0.x & 0xffffu); a1 += bf2f(u0.x >> 16);
        a2 += bf2f(u0.y & 0xffffu); a3 += bf2f(u0.y >> 16);
        a0 += bf2f(u1.x & 0xffffu); a1 += bf2f(u1.x >> 16);
        a2 += bf2f(u1.y & 0xffffu); a3 += bf2f(u1.y >> 16);
    }
    if (j < e) {
        int s0 = srcw[j];
        uint2 u0 = ((const uint2*)(hs + s0 * 16))[l8];
        if (l8 == 0) ad += dis[s0];
        a0 += bf2f(u0.x & 0xffffu); a1 += bf2f(u0.x >> 16);
        a2 += bf2f(u0.y & 0xffffu); a3 += bf2f(u0.y >> 16);
    }
    a0 += __shfl_xor(a0, 8);  a1 += __shfl_xor(a1, 8);
    a2 += __shfl_xor(a2, 8);  a3 += __shfl_xor(a3, 8);
    ad += __shfl_xor(ad, 8);
    a0 += __shfl_xor(a0, 16); a1 += __shfl_xor(a1, 16);
    a2 += __shfl_xor(a2, 16); a3 += __shfl_xor(a3, 16);
    ad += __shfl_xor(ad, 16);
    a0 += __shfl_xor(a0, 32); a1 += __shfl_xor(a1, 32);
    a2 += __shfl_xor(a2, 32); a3 += __shfl_xor(a3, 32);
    ad += __shfl_xor(ad, 32);
    if (e8 == 0) {
        float dc = dis[c];
        float4 w; w.x = dc * a0; w.y = dc * a1; w.z = dc * a2; w.w = dc * a3;
        *(float4*)(&G[c * 32 + l8 * 4]) = w;
        if (l8 == 0) Sd[c] = dc * (dc + ad);
    }
}

// ---------------- counts via binary search on sorted batch ----------------
__global__ void k_counts_bs(const int* __restrict__ batch, float* counts) {
    int g = threadIdx.x;
    if (g >= N_GRAPHS) return;
    int lo = 0, hi = N_NODES;
    while (lo < hi) { int mid = (lo + hi) >> 1; if (batch[mid] < g) lo = mid + 1; else hi = mid; }
    int start = lo;
    hi = N_NODES;
    while (lo < hi) { int mid = (lo + hi) >> 1; if (batch[mid] < g + 1) lo = mid + 1; else hi = mid; }
    counts[g] = (float)(lo - start);
}

// ---------------- fused lin2 + relu + mean-pool accumulate ----------------
__global__ __launch_bounds__(256) void k_lin2pool(const float* __restrict__ G,
        const float* __restrict__ Sd, const float* __restrict__ W2,
        const float* __restrict__ b2, const int* __restrict__ batch,
        float* __restrict__ sums) {
    __shared__ float w2t[H1F][H2F + 1];
    int tid = threadIdx.x;
    for (int idx = tid; idx < H2F * H1F; idx += 256) {
        int fo = idx >> 5, k = idx & 31;
        w2t[k][fo] = W2[idx];
    }
    __syncthreads();
    int f = tid & 63, sub = tid >> 6;
    float bfv = b2[f];
    int n0 = blockIdx.x * 256;
    float acc = 0.f; int gcur = -1;
    for (int i = sub; i < 256; i += 4) {
        int n = n0 + i;
        if (n >= N_NODES) break;
        const float4* Gr = (const float4*)(&G[n * 32]);
        float d = Sd[n] * bfv;
        #pragma unroll
        for (int q = 0; q < 8; ++q) {
            float4 v = Gr[q];
            d += v.x * w2t[4 * q][f] + v.y * w2t[4 * q + 1][f]
               + v.z * w2t[4 * q + 2][f] + v.w * w2t[4 * q + 3][f];
        }
        d = fmaxf(d, 0.f);
        int gg = batch[n];
        if (gg != gcur) {
            if (gcur >= 0) atomicAdd(&sums[gcur * H2F + f], acc);
            acc = 0.f; gcur = gg;
        }
        acc += d;
    }
    if (gcur >= 0) atomicAdd(&sums[gcur * H2F + f], acc);
}

// ---------------- final: mean, linear, softmax ----------------
__global__ __launch_bounds__(1024) void k_final(const float* __restrict__ sums,
        const float* __restrict__ counts, const float* __restrict__ Wf,
        const float* __restrict__ bf, float* __restrict__ out) {
    __shared__ float l[N_GRAPHS * N_CLASSES];
    int tid = threadIdx.x;
    if (tid < N_GRAPHS * N_CLASSES) {
        int g = tid / N_CLASSES, c = tid % N_CLASSES;
        float cnt = fmaxf(counts[g], 1.0f);
        float acc = bf[c];
        for (int f = 0; f < H2F; ++f)
            acc += (sums[g * H2F + f] / cnt) * Wf[c * H2F + f];
        l[tid] = acc;
    }
    __syncthreads();
    if (tid < N_GRAPHS) {
        float m = -1e30f;
        for (int c = 0; c < N_CLASSES; ++c) m = fmaxf(m, l[tid * N_CLASSES + c]);
        float s = 0.f;
        float ex[N_CLASSES];
        for (int c = 0; c < N_CLASSES; ++c) { ex[c] = expf(l[tid * N_CLASSES + c] - m); s += ex[c]; }
        for (int c = 0; c < N_CLASSES; ++c) out[tid * N_CLASSES + c] = ex[c] / s;
    }
}

extern "C" void kernel_launch(void* const* d_in, const int* in_sizes, int n_in,
                              void* d_out, int out_size, void* d_ws, size_t ws_size,
                              hipStream_t stream) {
    const float* x     = (const float*)d_in[0];
    const int*   ei    = (const int*)d_in[1];
    const int*   batch = (const int*)d_in[2];
    const float* W1    = (const float*)d_in[3];
    const float* b1    = (const float*)d_in[4];
    const float* W2    = (const float*)d_in[5];
    const float* b2    = (const float*)d_in[6];
    const float* Wf    = (const float*)d_in[7];
    const float* bf    = (const float*)d_in[8];
    float* out = (float*)d_out;

    const int* row = ei;            // edge_index[0,:] (source)
    const int* col = ei + N_EDGES;  // edge_index[1,:] (dest)

    // workspace layout (int units)
    int* W = (int*)d_ws;
    int*           ccount = W + 0;         // 391 (pad 400)
    int*           rcount = W + 400;
    int*           coff   = W + 800;       // 392
    int*           roff   = W + 1200;
    int*           cpos   = W + 1600;
    int*           rpos   = W + 2000;
    int*           off    = W + 2400;      // 100001 -> next 102408
    int*           srcw   = W + 102408;    // 3.2M -> 3302408
    unsigned*      partc  = (unsigned*)(W + 3302408);  // 3.2M u32 -> 6502408
    float*         G      = (float*)(W + 3302408);     // alias partc (dead after bucket_col)
    unsigned char* partr  = (unsigned char*)(W + 6502408);  // 3.2M u8 = 800000 ints -> 7302408
    float*         dis    = (float*)(W + 7302408);     // 100000
    float*         Sd     = (float*)(W + 7402408);     // 100000
    unsigned*      hs1b   = (unsigned*)(W + 7502408);  // 1.6M u32 -> 9102408
    unsigned*      hs2b   = (unsigned*)(W + 9102408);  // 1.6M u32 -> 10702408
    float*         sums   = (float*)(W + 10702408);    // 4096
    float*         cnts   = (float*)(W + 10706504);    // 64
    // total ~42.8 MB

    // ---- CSR build via 2-pass radix partition ----
    k_zero2<<<1, 256, 0, stream>>>(ccount, rcount);
    k_coarse<<<NPBC, 256, 0, stream>>>(row, col, ccount, rcount);
    k_cscan<<<1, 512, 0, stream>>>(ccount, rcount, coff, roff, cpos, rpos, sums, off);
    k_part<<<NPB, 256, 0, stream>>>(row, col, cpos, rpos, partc, partr);
    k_bucket_col<<<NBUCK, 256, 0, stream>>>(partc, coff, off, srcw);
    k_bucket_row<<<NBUCK, 256, 0, stream>>>(partr, roff, dis);

    // ---- layer 1 ----
    k_lin1<<<(N_NODES + 7) / 8, 256, 0, stream>>>(x, W1, b1, dis, hs1b);
    k_gather1<<<(N_NODES + 3) / 4, 256, 0, stream>>>(srcw, off, dis, hs1b, hs2b);

    // ---- layer 2 (aggregate in 32-dim, lin2 fused into pool) ----
    k_gather2<<<(N_NODES + 3) / 4, 256, 0, stream>>>(srcw, off, dis, hs2b, G, Sd);

    // ---- pooling + head ----
    k_counts_bs<<<1, 64, 0, stream>>>(batch, cnts);
    k_lin2pool<<<(N_NODES + 255) / 256, 256, 0, stream>>>(G, Sd, W2, b2, batch, sums);
    k_final<<<1, 640, 0, stream>>>(sums, cnts, Wf, bf, out);
}

// Round 10
// 307.493 us; speedup vs baseline: 1.2742x; 1.1659x over previous
//
#include <hip/hip_runtime.h>

#define N_NODES   100000
#define N_EDGES   3200000
#define D_IN      128
#define H1F       32
#define H2F       64
#define N_CLASSES 10
#define N_GRAPHS  64

#define NBUCK 391      // ceil(100000 / 256) buckets of 256 nodes
#define CAP   10240    // col slab capacity (u32); mean fill 8192, sigma~90
#define RCAP  10240    // row slab capacity (bytes)
#define EPB   3072
#define NPB   ((N_EDGES + EPB - 1) / EPB)   // 1042

// bf16 helpers (RNE pack)
__device__ __forceinline__ unsigned f2bf(float f) {
    unsigned u = __float_as_uint(f);
    return (u + 0x7fffu + ((u >> 16) & 1u)) >> 16;
}
__device__ __forceinline__ float bf2f(unsigned h) {
    return __uint_as_float(h << 16);
}

// ---------------- init: slab cursors + sums ----------------
__global__ void k_init(int* cpos, int* rpos, float* sums) {
    int t = threadIdx.x;
    for (int i = t; i < NBUCK; i += 512) { cpos[i] = i * CAP; rpos[i] = i * RCAP; }
    for (int i = t; i < N_GRAPHS * H2F; i += 512) sums[i] = 0.f;
}

// ---------------- LDS-staged partition into slabs (coalesced write-out) ----------------
__global__ __launch_bounds__(256) void k_part(const int* __restrict__ row,
        const int* __restrict__ col, int* cpos, int* rpos,
        unsigned* __restrict__ partc, unsigned char* __restrict__ partr) {
    __shared__ int sc[512], sr[512];            // histogram -> inclusive scan
    __shared__ int posc[NBUCK], posr[NBUCK];    // scatter cursors (local)
    __shared__ int basec[NBUCK], baser[NBUCK];  // global slab bases
    __shared__ unsigned stagc[EPB];             // 12.3 KB
    __shared__ unsigned char stagr[EPB];        // 3 KB
    int t = threadIdx.x;
    sc[t] = 0; sc[t + 256] = 0; sr[t] = 0; sr[t + 256] = 0;
    __syncthreads();
    int s = blockIdx.x * EPB;
    int e = min(s + EPB, N_EDGES);
    // phase A: local histograms
    for (int i = s + t; i < e; i += 256) {
        atomicAdd(&sc[col[i] >> 8], 1);
        atomicAdd(&sr[row[i] >> 8], 1);
    }
    __syncthreads();
    // phase B: inclusive scan over 512 (2 slots/thread)
    for (int o = 1; o < 512; o <<= 1) {
        int a0 = (t >= o) ? sc[t - o] : 0;
        int a1 = sc[t + 256 - o];
        int b0 = (t >= o) ? sr[t - o] : 0;
        int b1 = sr[t + 256 - o];
        __syncthreads();
        sc[t] += a0; sc[t + 256] += a1;
        sr[t] += b0; sr[t + 256] += b1;
        __syncthreads();
    }
    // phase C: per-bucket local starts + global slab reservations
    for (int b = t; b < NBUCK; b += 256) {
        int cc = sc[b] - (b ? sc[b - 1] : 0);
        int rc = sr[b] - (b ? sr[b - 1] : 0);
        posc[b] = sc[b] - cc;
        posr[b] = sr[b] - rc;
        basec[b] = cc ? atomicAdd(&cpos[b], cc) : 0;
        baser[b] = rc ? atomicAdd(&rpos[b], rc) : 0;
    }
    __syncthreads();
    // phase D: scatter into LDS staging (edge re-read is L2-hot)
    for (int i = s + t; i < e; i += 256) {
        int c = col[i], r = row[i];
        int b = c >> 8;
        int p = atomicAdd(&posc[b], 1);
        stagc[p] = ((unsigned)(c & 255) << 17) | (unsigned)r;  // row < 2^17
        int b2 = r >> 8;
        int p2 = atomicAdd(&posr[b2], 1);
        stagr[p2] = (unsigned char)(r & 255);
    }
    __syncthreads();
    // phase E: sorted write-out; bucket of position i via binary search on sc/sr
    int nloc = e - s;
    for (int i = t; i < nloc; i += 256) {
        int lo = 0, hi = NBUCK - 1;
        while (lo < hi) { int m = (lo + hi) >> 1; if (sc[m] > i) hi = m; else lo = m + 1; }
        int start = lo ? sc[lo - 1] : 0;
        partc[basec[lo] + (i - start)] = stagc[i];
    }
    for (int i = t; i < nloc; i += 256) {
        int lo = 0, hi = NBUCK - 1;
        while (lo < hi) { int m = (lo + hi) >> 1; if (sr[m] > i) hi = m; else lo = m + 1; }
        int start = lo ? sr[lo - 1] : 0;
        partr[baser[lo] + (i - start)] = stagr[i];
    }
}

// ---------------- per-bucket work: col -> CSR (srcoff + srcw); row -> dis ----------------
__global__ __launch_bounds__(256) void k_buckets(const unsigned* __restrict__ partc,
        const unsigned char* __restrict__ partr, const int* __restrict__ cpos,
        const int* __restrict__ rpos, int2* __restrict__ srcoff,
        int* __restrict__ srcw, float* __restrict__ dis) {
    int t = threadIdx.x;
    if (blockIdx.x < NBUCK) {
        // ---- col bucket: per-node counts, scan, sorted fill ----
        __shared__ int cnt[256], sc[256], run[256];
        int b = blockIdx.x;
        cnt[t] = 0; run[t] = 0;
        __syncthreads();
        int s = b * CAP, e = cpos[b];
        for (int i = s + t; i < e; i += 256)
            atomicAdd(&cnt[partc[i] >> 17], 1);
        __syncthreads();
        int v = cnt[t]; sc[t] = v; __syncthreads();
        for (int o = 1; o < 256; o <<= 1) {
            int a = (t >= o) ? sc[t - o] : 0;
            __syncthreads();
            sc[t] += a;
            __syncthreads();
        }
        int ex = sc[t] - v;
        __syncthreads();
        sc[t] = ex;
        __syncthreads();
        int n = (b << 8) + t;
        if (n < N_NODES) srcoff[n] = make_int2(s + ex, s + ex + v);
        for (int i = s + t; i < e; i += 256) {
            unsigned p = partc[i];
            int c = p >> 17;
            int k = atomicAdd(&run[c], 1);
            srcw[s + sc[c] + k] = (int)(p & 0x1FFFFu);
        }
    } else {
        // ---- row bucket: out-degree histogram -> dis ----
        __shared__ int cnt[256];
        int b = blockIdx.x - NBUCK;
        cnt[t] = 0;
        __syncthreads();
        int s = b * RCAP, e = rpos[b];
        for (int i = s + t; i < e; i += 256) atomicAdd(&cnt[partr[i]], 1);
        __syncthreads();
        int n = (b << 8) + t;
        if (n < N_NODES) dis[n] = rsqrtf((float)(1 + cnt[t]));  // +1 self-loop
    }
}

// ---------------- lin1: hs1b = bf16( dis[n] * (x W1^T + b1) ) ----------------
__global__ __launch_bounds__(256) void k_lin1(const float* __restrict__ x,
        const float* __restrict__ W1, const float* __restrict__ b1,
        const float* __restrict__ dis, unsigned* __restrict__ hs1b) {
    __shared__ float w1t[D_IN][H1F + 1];
    __shared__ float xs[8][D_IN];
    int tid = threadIdx.x;
    for (int idx = tid; idx < H1F * D_IN; idx += 256) {
        int f = idx >> 7, k = idx & 127;
        w1t[k][f] = W1[idx];
    }
    int nbase = blockIdx.x * 8;
    for (int idx = tid; idx < 8 * D_IN; idx += 256) {
        int nn = idx >> 7, k = idx & 127;
        int n = nbase + nn;
        xs[nn][k] = (n < N_NODES) ? x[(long long)n * D_IN + k] : 0.0f;
    }
    __syncthreads();
    int f = tid & 31, sub = tid >> 5;
    int n = nbase + sub;
    float acc = 0.f;
    #pragma unroll
    for (int k = 0; k < D_IN; ++k) acc += xs[sub][k] * w1t[k][f];
    float val = (n < N_NODES) ? dis[n] * (acc + b1[f]) : 0.f;
    float other = __shfl_xor(val, 1);
    if ((f & 1) == 0 && n < N_NODES)
        hs1b[n * 16 + (f >> 1)] = f2bf(val) | (f2bf(other) << 16);
}

// ---------------- gather1: hs2b = bf16( dis_c * relu( dis_c*(hs1_c + sum hs1_src) ) ) ----
// one wave per node; 8 groups of 8 lanes, each group one edge (uint2/lane = 64B row);
// 2-way unroll => 16 edge-gathers in flight per wave
__global__ __launch_bounds__(256) void k_gather1(const int* __restrict__ srcw,
        const int2* __restrict__ srcoff, const float* __restrict__ dis,
        const unsigned* __restrict__ hs, unsigned* __restrict__ out) {
    int lane = threadIdx.x & 63;
    int c = (blockIdx.x * 256 + threadIdx.x) >> 6;
    if (c >= N_NODES) return;
    int e8 = lane >> 3, l8 = lane & 7;
    int2 so = srcoff[c];
    int s = so.x, e = so.y;
    float a0 = 0.f, a1 = 0.f, a2 = 0.f, a3 = 0.f;
    if (e8 == 0) {
        uint2 u = ((const uint2*)(hs + c * 16))[l8];
        a0 = bf2f(u.x & 0xffffu); a1 = bf2f(u.x >> 16);
        a2 = bf2f(u.y & 0xffffu); a3 = bf2f(u.y >> 16);
    }
    int j = s + e8;
    for (; j + 8 < e; j += 16) {
        int s0 = srcw[j], s1 = srcw[j + 8];
        uint2 u0 = ((const uint2*)(hs + s0 * 16))[l8];
        uint2 u1 = ((const uint2*)(hs + s1 * 16))[l8];
        a0 += bf2f(u0.x & 0xffffu); a1 += bf2f(u0.x >> 16);
        a2 += bf2f(u0.y & 0xffffu); a3 += bf2f(u0.y >> 16);
        a0 += bf2f(u1.x & 0xffffu); a1 += bf2f(u1.x >> 16);
        a2 += bf2f(u1.y & 0xffffu); a3 += bf2f(u1.y >> 16);
    }
    if (j < e) {
        uint2 u0 = ((const uint2*)(hs + srcw[j] * 16))[l8];
        a0 += bf2f(u0.x & 0xffffu); a1 += bf2f(u0.x >> 16);
        a2 += bf2f(u0.y & 0xffffu); a3 += bf2f(u0.y >> 16);
    }
    a0 += __shfl_xor(a0, 8);  a1 += __shfl_xor(a1, 8);
    a2 += __shfl_xor(a2, 8);  a3 += __shfl_xor(a3, 8);
    a0 += __shfl_xor(a0, 16); a1 += __shfl_xor(a1, 16);
    a2 += __shfl_xor(a2, 16); a3 += __shfl_xor(a3, 16);
    a0 += __shfl_xor(a0, 32); a1 += __shfl_xor(a1, 32);
    a2 += __shfl_xor(a2, 32); a3 += __shfl_xor(a3, 32);
    if (e8 == 0) {
        float dc = dis[c];
        uint2 w;
        w.x = f2bf(dc * fmaxf(dc * a0, 0.f)) | (f2bf(dc * fmaxf(dc * a1, 0.f)) << 16);
        w.y = f2bf(dc * fmaxf(dc * a2, 0.f)) | (f2bf(dc * fmaxf(dc * a3, 0.f)) << 16);
        ((uint2*)(out + c * 16))[l8] = w;
    }
}

// ---------------- gather2: G = dis_c*(hs2_c + sum hs2_src) [32 fp32], Sd = dis_c*(dis_c+sum dis_src)
__global__ __launch_bounds__(256) void k_gather2(const int* __restrict__ srcw,
        const int2* __restrict__ srcoff, const float* __restrict__ dis,
        const unsigned* __restrict__ hs, float* __restrict__ G,
        float* __restrict__ Sd) {
    int lane = threadIdx.x & 63;
    int c = (blockIdx.x * 256 + threadIdx.x) >> 6;
    if (c >= N_NODES) return;
    int e8 = lane >> 3, l8 = lane & 7;
    int2 so = srcoff[c];
    int s = so.x, e = so.y;
    float a0 = 0.f, a1 = 0.f, a2 = 0.f, a3 = 0.f, ad = 0.f;
    if (e8 == 0) {
        uint2 u = ((const uint2*)(hs + c * 16))[l8];
        a0 = bf2f(u.x & 0xffffu); a1 = bf2f(u.x >> 16);
        a2 = bf2f(u.y & 0xffffu); a3 = bf2f(u.y >> 16);
    }
    int j = s + e8;
    for (; j + 8 < e; j += 16) {
        int s0 = srcw[j], s1 = srcw[j + 8];
        uint2 u0 = ((const uint2*)(hs + s0 * 16))[l8];
        uint2 u1 = ((const uint2*)(hs + s1 * 16))[l8];
        if (l8 == 0) ad += dis[s0] + dis[s1];
        a0 += bf2f(u0.x & 0xffffu); a1 += bf2f(u0.x >> 16);
        a2 += bf2f(u0.y & 0xffffu); a3 += bf2f(u0.y >> 16);
        a0 += bf2f(u1.x & 0xffffu); a1 += bf2f(u1.x >> 16);
        a2 += bf2f(u1.y & 0xffffu); a3 += bf2f(u1.y >> 16);
    }
    if (j < e) {
        int s0 = srcw[j];
        uint2 u0 = ((const uint2*)(hs + s0 * 16))[l8];
        if (l8 == 0) ad += dis[s0];
        a0 += bf2f(u0.x & 0xffffu); a1 += bf2f(u0.x >> 16);
        a2 += bf2f(u0.y & 0xffffu); a3 += bf2f(u0.y >> 16);
    }
    a0 += __shfl_xor(a0, 8);  a1 += __shfl_xor(a1, 8);
    a2 += __shfl_xor(a2, 8);  a3 += __shfl_xor(a3, 8);
    ad += __shfl_xor(ad, 8);
    a0 += __shfl_xor(a0, 16); a1 += __shfl_xor(a1, 16);
    a2 += __shfl_xor(a2, 16); a3 += __shfl_xor(a3, 16);
    ad += __shfl_xor(ad, 16);
    a0 += __shfl_xor(a0, 32); a1 += __shfl_xor(a1, 32);
    a2 += __shfl_xor(a2, 32); a3 += __shfl_xor(a3, 32);
    ad += __shfl_xor(ad, 32);
    if (e8 == 0) {
        float dc = dis[c];
        float4 w; w.x = dc * a0; w.y = dc * a1; w.z = dc * a2; w.w = dc * a3;
        *(float4*)(&G[c * 32 + l8 * 4]) = w;
        if (l8 == 0) Sd[c] = dc * (dc + ad);
    }
}

// ---------------- fused lin2 + relu + mean-pool accumulate ----------------
__global__ __launch_bounds__(256) void k_lin2pool(const float* __restrict__ G,
        const float* __restrict__ Sd, const float* __restrict__ W2,
        const float* __restrict__ b2, const int* __restrict__ batch,
        float* __restrict__ sums) {
    __shared__ float w2t[H1F][H2F + 1];
    int tid = threadIdx.x;
    for (int idx = tid; idx < H2F * H1F; idx += 256) {
        int fo = idx >> 5, k = idx & 31;
        w2t[k][fo] = W2[idx];
    }
    __syncthreads();
    int f = tid & 63, sub = tid >> 6;
    float bfv = b2[f];
    int n0 = blockIdx.x * 256;
    float acc = 0.f; int gcur = -1;
    for (int i = sub; i < 256; i += 4) {
        int n = n0 + i;
        if (n >= N_NODES) break;
        const float4* Gr = (const float4*)(&G[n * 32]);
        float d = Sd[n] * bfv;
        #pragma unroll
        for (int q = 0; q < 8; ++q) {
            float4 v = Gr[q];
            d += v.x * w2t[4 * q][f] + v.y * w2t[4 * q + 1][f]
               + v.z * w2t[4 * q + 2][f] + v.w * w2t[4 * q + 3][f];
        }
        d = fmaxf(d, 0.f);
        int gg = batch[n];
        if (gg != gcur) {
            if (gcur >= 0) atomicAdd(&sums[gcur * H2F + f], acc);
            acc = 0.f; gcur = gg;
        }
        acc += d;
    }
    if (gcur >= 0) atomicAdd(&sums[gcur * H2F + f], acc);
}

// ---------------- final: counts (binary search) + mean + linear + softmax ----------------
__global__ __launch_bounds__(640) void k_final(const float* __restrict__ sums,
        const int* __restrict__ batch, const float* __restrict__ Wf,
        const float* __restrict__ bf, float* __restrict__ out) {
    __shared__ float l[N_GRAPHS * N_CLASSES];
    __shared__ float cnts[N_GRAPHS];
    int tid = threadIdx.x;
    if (tid < N_GRAPHS) {
        int g = tid;
        int lo = 0, hi = N_NODES;
        while (lo < hi) { int mid = (lo + hi) >> 1; if (batch[mid] < g) lo = mid + 1; else hi = mid; }
        int start = lo;
        hi = N_NODES;
        while (lo < hi) { int mid = (lo + hi) >> 1; if (batch[mid] < g + 1) lo = mid + 1; else hi = mid; }
        cnts[g] = (float)(lo - start);
    }
    __syncthreads();
    if (tid < N_GRAPHS * N_CLASSES) {
        int g = tid / N_CLASSES, c = tid % N_CLASSES;
        float cnt = fmaxf(cnts[g], 1.0f);
        float acc = bf[c];
        for (int f = 0; f < H2F; ++f)
            acc += (sums[g * H2F + f] / cnt) * Wf[c * H2F + f];
        l[tid] = acc;
    }
    __syncthreads();
    if (tid < N_GRAPHS) {
        float m = -1e30f;
        for (int c = 0; c < N_CLASSES; ++c) m = fmaxf(m, l[tid * N_CLASSES + c]);
        float s = 0.f;
        float ex[N_CLASSES];
        for (int c = 0; c < N_CLASSES; ++c) { ex[c] = expf(l[tid * N_CLASSES + c] - m); s += ex[c]; }
        for (int c = 0; c < N_CLASSES; ++c) out[tid * N_CLASSES + c] = ex[c] / s;
    }
}

extern "C" void kernel_launch(void* const* d_in, const int* in_sizes, int n_in,
                              void* d_out, int out_size, void* d_ws, size_t ws_size,
                              hipStream_t stream) {
    const float* x     = (const float*)d_in[0];
    const int*   ei    = (const int*)d_in[1];
    const int*   batch = (const int*)d_in[2];
    const float* W1    = (const float*)d_in[3];
    const float* b1    = (const float*)d_in[4];
    const float* W2    = (const float*)d_in[5];
    const float* b2    = (const float*)d_in[6];
    const float* Wf    = (const float*)d_in[7];
    const float* bf    = (const float*)d_in[8];
    float* out = (float*)d_out;

    const int* row = ei;            // edge_index[0,:] (source)
    const int* col = ei + N_EDGES;  // edge_index[1,:] (dest)

    // workspace layout (int units)
    int* W = (int*)d_ws;
    int*           cpos   = W + 0;          // 391 (pad 400)
    int*           rpos   = W + 400;        // 391 (pad 400)
    int2*          srcoff = (int2*)(W + 800);              // 100000 int2 -> 200800
    int*           srcw   = W + 200800;     // slab 391*10240 = 4003840 -> 4204640
    unsigned*      partc  = (unsigned*)(W + 4204640);      // slab 4003840 -> 8208480
    float*         G      = (float*)(W + 4204640);         // alias partc (dead after k_buckets)
    unsigned char* partr  = (unsigned char*)(W + 8208480); // slab 391*10240 B -> +1000960 = 9209440
    float*         dis    = (float*)(W + 9209440);         // 100000
    float*         Sd     = (float*)(W + 9309440);         // 100000
    unsigned*      hs1b   = (unsigned*)(W + 9409440);      // 1.6M -> 11009440
    unsigned*      hs2b   = (unsigned*)(W + 11009440);     // 1.6M -> 12609440
    float*         sums   = (float*)(W + 12609440);        // 4096
    // total ~50.5 MB

    // ---- CSR build: slab partition + per-bucket sort ----
    k_init<<<1, 512, 0, stream>>>(cpos, rpos, sums);
    k_part<<<NPB, 256, 0, stream>>>(row, col, cpos, rpos, partc, partr);
    k_buckets<<<2 * NBUCK, 256, 0, stream>>>(partc, partr, cpos, rpos, srcoff, srcw, dis);

    // ---- layer 1 ----
    k_lin1<<<(N_NODES + 7) / 8, 256, 0, stream>>>(x, W1, b1, dis, hs1b);
    k_gather1<<<(N_NODES + 3) / 4, 256, 0, stream>>>(srcw, srcoff, dis, hs1b, hs2b);

    // ---- layer 2 (aggregate in 32-dim, lin2 fused into pool) ----
    k_gather2<<<(N_NODES + 3) / 4, 256, 0, stream>>>(srcw, srcoff, dis, hs2b, G, Sd);

    // ---- pooling + head ----
    k_lin2pool<<<(N_NODES + 255) / 256, 256, 0, stream>>>(G, Sd, W2, b2, batch, sums);
    k_final<<<1, 640, 0, stream>>>(sums, batch, Wf, bf, out);
}